// Round 14
// baseline (1498.215 us; speedup 1.0000x reference)
//
#include <hip/hip_runtime.h>
#include <hip/hip_bf16.h>

constexpr int kB = 32;
constexpr int kN = 256;
constexpr int kR = 2048;
constexpr int kD = 1024;

typedef short bf16x8 __attribute__((ext_vector_type(8)));
typedef float f32x4 __attribute__((ext_vector_type(4)));
typedef unsigned short u16x8 __attribute__((ext_vector_type(8)));

__device__ __forceinline__ unsigned short f2bf(float f) {
  union { __hip_bfloat16 h; unsigned short u; } cv;
  cv.h = __float2bfloat16(f);
  return cv.u;
}

__device__ __forceinline__ void gload_lds16(const void* g, void* l) {
  __builtin_amdgcn_global_load_lds(
      (const __attribute__((address_space(1))) unsigned int*)g,
      (__attribute__((address_space(3))) unsigned int*)l, 16, 0, 0);
}

#define FENCE asm volatile("" ::: "memory")
#define LGKM0 asm volatile("s_waitcnt lgkmcnt(0)" ::: "memory")
#define WAITV(n) asm volatile("s_waitcnt vmcnt(" #n ")" ::: "memory")

// ---------------------------------------------------------------------------
// Fused f32->bf16 pre-pass for all 5 GEMM operands + out0 passthrough copy.
// ---------------------------------------------------------------------------
__global__ void cvt_all(const float* __restrict__ obj,
                        const float* __restrict__ attr,
                        const float* __restrict__ rela,
                        const float* __restrict__ wa,
                        const float* __restrict__ wr,
                        unsigned short* __restrict__ objb,
                        unsigned short* __restrict__ attrb,
                        unsigned short* __restrict__ relab,
                        unsigned short* __restrict__ wab,
                        unsigned short* __restrict__ wrb,
                        float* __restrict__ out0) {
  constexpr long n0 = (long)kB * kN * kD / 8;          // obj
  constexpr long c0 = n0;
  constexpr long c1 = c0 + n0;                          // attr
  constexpr long c2 = c1 + (long)kB * kR * kD / 8;      // rela
  constexpr long c3 = c2 + (long)kD * 2 * kD / 8;       // W_attr
  constexpr long c4 = c3 + (long)kD * 3 * kD / 8;       // W_rela
  const long stride = (long)gridDim.x * blockDim.x;
  for (long i = (long)blockIdx.x * blockDim.x + threadIdx.x; i < c4;
       i += stride) {
    const float* s;
    unsigned short* d;
    long j;
    bool isobj = false;
    if (i < c0)      { s = obj;  d = objb;  j = i; isobj = true; }
    else if (i < c1) { s = attr; d = attrb; j = i - c0; }
    else if (i < c2) { s = rela; d = relab; j = i - c1; }
    else if (i < c3) { s = wa;   d = wab;   j = i - c2; }
    else             { s = wr;   d = wrb;   j = i - c3; }
    const float4 a = reinterpret_cast<const float4*>(s)[2 * j];
    const float4 b = reinterpret_cast<const float4*>(s)[2 * j + 1];
    if (isobj) {  // out0 = obj passthrough, fused with the convert read
      reinterpret_cast<float4*>(out0)[2 * j] = a;
      reinterpret_cast<float4*>(out0)[2 * j + 1] = b;
    }
    u16x8 v;
    v[0] = f2bf(a.x); v[1] = f2bf(a.y); v[2] = f2bf(a.z); v[3] = f2bf(a.w);
    v[4] = f2bf(b.x); v[5] = f2bf(b.y); v[6] = f2bf(b.z); v[7] = f2bf(b.w);
    reinterpret_cast<u16x8*>(d)[j] = v;
  }
}

// ---------------------------------------------------------------------------
// 128x256 bf16 GEMM body, 8 waves (2M x 4N, 64x64 each), BK=32, 3-slot LDS
// ring (3 x 24 KB = 72 KB -> 2 BLOCKS/CU: 144 KB LDS, <=128 regs/wave =
// acc 64 AGPR + ~50 arch VGPR). Cross-block TLP supplies the MFMA/LDS
// overlap (m114) that single-block schedules couldn't (~44% MfmaUtil cap).
// Per tile t (slot s = t%3), depth-2 counted pipeline, R4-proven sync order:
//   WAITV(3)           [OWN tile-t loads landed; tile-t+1's stay in flight]
//   lgkm0 + barrier    [=> ALL waves' tile-t loads landed (RAW), and all
//                       reads of slot(t-1) retired (WAR)]
//   issue(t+2 -> slot(t-1))   [3 gload_lds rounds: 1 A(128x32) + 2 B(256x32)]
//   compute(t from slot s)    [8 ds_read_b128 + 16 MFMA/wave, setprio]
// vmcnt never drains mid-loop.
// R12/R13 BUG FIXED HERE: A-staging wave base is w*512 shorts (16 rows x 32
// shorts/row), not w*1024 — the stale 32-row stride made waves 4-7 overwrite
// the B region and left A rows 64..127 unwritten (inf on output 1).
// Staging rows w*16+(l>>2), granule l&3; source pre-swizzle
// ((l&3)^((l>>3)&3))<<4; read swizzle (lgrp^((lrow>>1)&3))<<3 — the
// rounds-4..8 verified 0-conflict geometry (XOR key = row bits 1-2, which
// come from l>>2 identically on write and read sides here).
// C[m,d] = relu(sum_k A[m,k]*W[d,k] + bias[d]) + resid[m,d]  (*mask[m] rela)
// A row = concat of 1024-wide segments (32 BK-tiles each):
//   attr: [objb m, attrb m]                 (K=2048, T=64)
//   rela: [objb[subj], relab m, objb[obji]] (K=3072, T=96)
// ---------------------------------------------------------------------------
template <bool IS_RELA, int K_TOT, int LOG_RPB, int NPANEL>
__device__ __forceinline__ void gemm_body(
    int bid, unsigned short* smem,
    const unsigned short* __restrict__ objb,
    const unsigned short* __restrict__ seg1b,
    const unsigned short* __restrict__ Wb,
    const int* __restrict__ edges, const float* __restrict__ masks,
    const float* __restrict__ resid, const float* __restrict__ bias,
    float* __restrict__ out) {
  constexpr int T = K_TOT / 32;

  // XCD mapping: XCD x owns col panel (x>>1); (x&1) splits row panels.
  const int x = bid & 7;
  const int col0 = (x >> 1) * 256;
  const int panel = (x & 1) * (NPANEL / 2) + (bid >> 3);
  const int row0 = panel * 128;

  const int tid = threadIdx.x;
  const int w = tid >> 6;   // wave 0..7
  const int l = tid & 63;

  // source granule pre-swizzle (rule #21), proven formula
  const int sw = (((l & 3) ^ ((l >> 3) & 3)) << 4);  // bytes

  // A staging: ONE round covers 128 rows x 4 granules; thread row w*16+(l>>2)
  uint32_t oA0, oA1, oA2;
  {
    const int m = row0 + w * 16 + (l >> 2);
    if constexpr (IS_RELA) {
      const int b = m >> LOG_RPB;
      const int ri = m & ((1 << LOG_RPB) - 1);
      const int2 e =
          *reinterpret_cast<const int2*>(&edges[((size_t)b * kR + ri) * 2]);
      oA0 = (uint32_t)((b * kN + e.x) * kD) * 2u;
      oA1 = (uint32_t)((size_t)m * kD * 2);
      oA2 = (uint32_t)((b * kN + e.y) * kD) * 2u;
    } else {
      oA0 = (uint32_t)((size_t)m * kD * 2);
      oA1 = oA0;
      oA2 = 0;
    }
  }
  // B staging: TWO rounds cover 256 rows; round r row = r*128 + w*16 + (l>>2)
  uint32_t oB[2];
#pragma unroll
  for (int r = 0; r < 2; ++r) {
    const int rl = r * 128 + w * 16 + (l >> 2);
    oB[r] = (uint32_t)((size_t)(col0 + rl) * K_TOT * 2);
  }

  const int wr = w >> 2;        // 0..1 (M half)
  const int wc = w & 3;         // 0..3 (N quarter)
  const int lrow = l & 15;
  const int lgrp = l >> 4;
  const int pgr = ((lgrp ^ ((lrow >> 1) & 3)) << 3);  // shorts

  f32x4 acc[4][4] = {};

  // slot layout (shorts): s*12288 + { A[128][32]:0 , B[256][32]:4096 }
  auto issue = [&](int tn, int slot) {
    unsigned short* ra = smem + slot * 12288;
    unsigned short* rb = ra + 4096;
    const int seg = tn >> 5;                        // wave-uniform
    const uint32_t ko = (uint32_t)(tn & 31) << 6;   // bytes in segment row
    const uint32_t kb = (uint32_t)tn << 6;          // bytes in W row
    const char* srcA;
    if constexpr (IS_RELA) {
      srcA = (seg == 1) ? (const char*)seg1b + oA1
                        : (const char*)objb + (seg == 0 ? oA0 : oA2);
    } else {
      srcA = (seg == 0) ? (const char*)objb + oA0
                        : (const char*)seg1b + oA1;
    }
    gload_lds16(srcA + ko + sw, ra + w * 512);  // 16 rows x 32 shorts / wave
#pragma unroll
    for (int r = 0; r < 2; ++r)
      gload_lds16((const char*)Wb + oB[r] + kb + sw,
                  rb + (r * 128 + w * 16) * 32);
  };

  auto compute = [&](int slot) {
    const unsigned short* da = smem + slot * 12288;
    const unsigned short* db = da + 4096;
    bf16x8 bf[4], af[4];
#pragma unroll
    for (int ni = 0; ni < 4; ++ni)
      bf[ni] = *reinterpret_cast<const bf16x8*>(
          &db[(wc * 64 + ni * 16 + lrow) * 32 + pgr]);
#pragma unroll
    for (int mi = 0; mi < 4; ++mi)
      af[mi] = *reinterpret_cast<const bf16x8*>(
          &da[(wr * 64 + mi * 16 + lrow) * 32 + pgr]);
    __builtin_amdgcn_s_setprio(1);
#pragma unroll
    for (int mi = 0; mi < 4; ++mi)
#pragma unroll
      for (int ni = 0; ni < 4; ++ni)
        acc[mi][ni] = __builtin_amdgcn_mfma_f32_16x16x32_bf16(
            af[mi], bf[ni], acc[mi][ni], 0, 0, 0);
    __builtin_amdgcn_s_setprio(0);
  };

  // prologue: tiles 0,1 in flight (depth 2)
  issue(0, 0);
  issue(1, 1);

  // main loop: tiles 0 .. T-3; runtime slot ring
  int sc = 0;  // slot of tile t
#pragma unroll 1
  for (int t = 0; t < T - 2; ++t) {
    WAITV(3);                                   // own tile-t loads landed
    LGKM0; __builtin_amdgcn_s_barrier(); FENCE; // all waves: RAW + WAR
    int s2 = sc + 2; if (s2 >= 3) s2 -= 3;      // slot of t+2 == slot of t-1
    issue(t + 2, s2);
    compute(sc);
    ++sc; if (sc == 3) sc = 0;
  }
  // tile T-2
  WAITV(3);
  LGKM0; __builtin_amdgcn_s_barrier(); FENCE;
  compute(sc);
  ++sc; if (sc == 3) sc = 0;
  // tile T-1
  WAITV(0);
  LGKM0; __builtin_amdgcn_s_barrier(); FENCE;
  compute(sc);

  // epilogue: bias + relu + residual (+mask)
  float biasv[4];
#pragma unroll
  for (int ni = 0; ni < 4; ++ni)
    biasv[ni] = bias[col0 + wc * 64 + ni * 16 + lrow];

#pragma unroll
  for (int mi = 0; mi < 4; ++mi) {
#pragma unroll
    for (int jj = 0; jj < 4; ++jj) {
      const int m = row0 + wr * 64 + mi * 16 + lgrp * 4 + jj;
      const size_t ro = (size_t)m * kD;
      float mk = 1.0f;
      if constexpr (IS_RELA) mk = masks[m];
#pragma unroll
      for (int ni = 0; ni < 4; ++ni) {
        const int col = col0 + wc * 64 + ni * 16 + lrow;
        float v = acc[mi][ni][jj] + biasv[ni];
        v = fmaxf(v, 0.0f) + resid[ro + col];
        if constexpr (IS_RELA) v *= mk;
        out[ro + col] = v;
      }
    }
  }
}

// ---------------------------------------------------------------------------
// Fused launch: blocks 0..2047 = rela (512 row-panels x 4 col-panels),
// 2048..2303 = attr (64 x 4). 72 KB LDS + <=128 regs/wave -> 2 blocks/CU.
// ---------------------------------------------------------------------------
__global__ __launch_bounds__(512, 4) void gnn_fused(
    const unsigned short* __restrict__ objb,
    const unsigned short* __restrict__ attrb,
    const unsigned short* __restrict__ relab,
    const unsigned short* __restrict__ wab,
    const unsigned short* __restrict__ wrb,
    const int* __restrict__ edges, const float* __restrict__ masks,
    const float* __restrict__ attr, const float* __restrict__ rela,
    const float* __restrict__ b_attr, const float* __restrict__ b_rela,
    float* __restrict__ out1, float* __restrict__ out2) {
  extern __shared__ unsigned short smem[];
  const int bid = blockIdx.x;
  if (bid < 2048) {
    gemm_body<true, 3072, 11, 512>(bid, smem, objb, relab, wrb, edges, masks,
                                   rela, b_rela, out2);
  } else {
    gemm_body<false, 2048, 8, 64>(bid - 2048, smem, objb, attrb, wab, nullptr,
                                  nullptr, attr, b_attr, out1);
  }
}

extern "C" void kernel_launch(void* const* d_in, const int* in_sizes, int n_in,
                              void* d_out, int out_size, void* d_ws,
                              size_t ws_size, hipStream_t stream) {
  (void)in_sizes; (void)n_in; (void)out_size; (void)ws_size;
  const float* obj = (const float*)d_in[0];
  const float* attr = (const float*)d_in[1];
  const float* rela = (const float*)d_in[2];
  const int* edges = (const int*)d_in[3];
  const float* masks = (const float*)d_in[4];
  const float* W_attr = (const float*)d_in[5];
  const float* b_attr = (const float*)d_in[6];
  const float* W_rela = (const float*)d_in[7];
  const float* b_rela = (const float*)d_in[8];

  float* out0 = (float*)d_out;
  float* out1 = out0 + (size_t)kB * kN * kD;
  float* out2 = out1 + (size_t)kB * kN * kD;

  constexpr size_t nObj = (size_t)kB * kN * kD;
  constexpr size_t nRela = (size_t)kB * kR * kD;
  constexpr size_t nWa = (size_t)kD * 2 * kD;

  unsigned short* objb = (unsigned short*)d_ws;
  unsigned short* attrb = objb + nObj;
  unsigned short* relab = attrb + nObj;
  unsigned short* wab = relab + nRela;
  unsigned short* wrb = wab + nWa;

  cvt_all<<<2048, 256, 0, stream>>>(obj, attr, rela, W_attr, W_rela, objb,
                                    attrb, relab, wab, wrb, out0);

  constexpr int kSmem = 73728;  // 3 slots x 24 KB -> 2 blocks/CU (144 KB)
  hipFuncSetAttribute((const void*)gnn_fused,
                      hipFuncAttributeMaxDynamicSharedMemorySize, kSmem);
  gnn_fused<<<2304, 512, kSmem, stream>>>(objb, attrb, relab, wab, wrb, edges,
                                          masks, attr, rela, b_attr, b_rela,
                                          out1, out2);
}

// Round 15
// 567.232 us; speedup vs baseline: 2.6413x; 2.6413x over previous
//
#include <hip/hip_runtime.h>
#include <hip/hip_bf16.h>

constexpr int kB = 32;
constexpr int kN = 256;
constexpr int kR = 2048;
constexpr int kD = 1024;

typedef short bf16x8 __attribute__((ext_vector_type(8)));
typedef float f32x4 __attribute__((ext_vector_type(4)));
typedef unsigned short u16x8 __attribute__((ext_vector_type(8)));

__device__ __forceinline__ unsigned short f2bf(float f) {
  union { __hip_bfloat16 h; unsigned short u; } cv;
  cv.h = __float2bfloat16(f);
  return cv.u;
}

__device__ __forceinline__ void gload_lds16(const void* g, void* l) {
  __builtin_amdgcn_global_load_lds(
      (const __attribute__((address_space(1))) unsigned int*)g,
      (__attribute__((address_space(3))) unsigned int*)l, 16, 0, 0);
}

#define FENCE asm volatile("" ::: "memory")
#define WAITV(n) asm volatile("s_waitcnt vmcnt(" #n ")" ::: "memory")

// ---------------------------------------------------------------------------
// Fused f32->bf16 pre-pass for all 5 GEMM operands + out0 passthrough copy.
// ---------------------------------------------------------------------------
__global__ void cvt_all(const float* __restrict__ obj,
                        const float* __restrict__ attr,
                        const float* __restrict__ rela,
                        const float* __restrict__ wa,
                        const float* __restrict__ wr,
                        unsigned short* __restrict__ objb,
                        unsigned short* __restrict__ attrb,
                        unsigned short* __restrict__ relab,
                        unsigned short* __restrict__ wab,
                        unsigned short* __restrict__ wrb,
                        float* __restrict__ out0) {
  constexpr long n0 = (long)kB * kN * kD / 8;          // obj
  constexpr long c0 = n0;
  constexpr long c1 = c0 + n0;                          // attr
  constexpr long c2 = c1 + (long)kB * kR * kD / 8;      // rela
  constexpr long c3 = c2 + (long)kD * 2 * kD / 8;       // W_attr
  constexpr long c4 = c3 + (long)kD * 3 * kD / 8;       // W_rela
  const long stride = (long)gridDim.x * blockDim.x;
  for (long i = (long)blockIdx.x * blockDim.x + threadIdx.x; i < c4;
       i += stride) {
    const float* s;
    unsigned short* d;
    long j;
    bool isobj = false;
    if (i < c0)      { s = obj;  d = objb;  j = i; isobj = true; }
    else if (i < c1) { s = attr; d = attrb; j = i - c0; }
    else if (i < c2) { s = rela; d = relab; j = i - c1; }
    else if (i < c3) { s = wa;   d = wab;   j = i - c2; }
    else             { s = wr;   d = wrb;   j = i - c3; }
    const float4 a = reinterpret_cast<const float4*>(s)[2 * j];
    const float4 b = reinterpret_cast<const float4*>(s)[2 * j + 1];
    if (isobj) {  // out0 = obj passthrough, fused with the convert read
      reinterpret_cast<float4*>(out0)[2 * j] = a;
      reinterpret_cast<float4*>(out0)[2 * j + 1] = b;
    }
    u16x8 v;
    v[0] = f2bf(a.x); v[1] = f2bf(a.y); v[2] = f2bf(a.z); v[3] = f2bf(a.w);
    v[4] = f2bf(b.x); v[5] = f2bf(b.y); v[6] = f2bf(b.z); v[7] = f2bf(b.w);
    reinterpret_cast<u16x8*>(d)[j] = v;
  }
}

// ---------------------------------------------------------------------------
// 256x256 bf16 GEMM body — the verified best (R8): BK=64 super-tiles
// (2 proven BK=32 halves), 2-slot LDS double buffer (2 x 64 KB), counted
// vmcnt(4), one-phase-ahead register reads, setprio-wrapped MFMA clusters,
// 2 barriers per 64 K-units.
// Per super-tile t (slot S=t&1), 4 sub-phases; issue order Ah0,Bh0,Ah1,Bh1
// of tile t+1 spread one-per-sub-phase:
//   sp0: issue Ah0(t+1) | pre-read A4-7@k0(t)        | MFMA k0 mi0-3
//   sp1: issue Bh0(t+1) | WAITV(4)+bar [Ah1,Bh1(t) resident]
//        | pre-read A0-3@k1 + B@k1 (t)               | MFMA k0 mi4-7
//   sp2: issue Ah1(t+1) | pre-read A4-7@k1(t)        | MFMA k1 mi0-3
//   sp3: issue Bh1(t+1) | WAITV(4)+bar [Ah0,Bh0(t+1) resident]
//        | pre-read A0-3@k0 + B@k0 (t+1, slot S^1)   | MFMA k1 mi4-7
// WAITV before barrier => own-loads-landed + barrier => all waves' loads
// landed (RAW); reads retire before their consuming MFMA which precedes the
// barrier preceding any overwrite (WAR). vmcnt never drains mid-loop.
// Staging/read/swizzle geometry: rounds 4-8 verified, 0 bank conflicts.
// C[m,d] = relu(sum_k A[m,k]*W[d,k] + bias[d]) + resid[m,d]  (*mask[m] rela)
// A row = concat of 1024-wide segments:
//   attr: [objb m, attrb m]                 (K=2048, T=32)
//   rela: [objb[subj], relab m, objb[obji]] (K=3072, T=48)
// ---------------------------------------------------------------------------
template <bool IS_RELA, int K_TOT, int LOG_RPB, int NPANEL>
__device__ __forceinline__ void gemm_body(
    int bid, unsigned short* smem,
    const unsigned short* __restrict__ objb,
    const unsigned short* __restrict__ seg1b,
    const unsigned short* __restrict__ Wb,
    const int* __restrict__ edges, const float* __restrict__ masks,
    const float* __restrict__ resid, const float* __restrict__ bias,
    float* __restrict__ out) {
  constexpr int T = K_TOT / 64;  // super-tiles

  // XCD mapping: XCD x owns col panel (x>>1); (x&1) splits row panels.
  const int x = bid & 7;
  const int col0 = (x >> 1) * 256;
  const int panel = (x & 1) * (NPANEL / 2) + (bid >> 3);
  const int row0 = panel * 256;

  const int tid = threadIdx.x;
  const int w = tid >> 6;   // wave 0..7
  const int l = tid & 63;

  // staging: round r in {0,1} of a half covers LDS rows (w*32 + r*16 + l>>2),
  // granule l&3 (16B); source pre-swizzle g = (l&3) ^ ((l>>3)&3) (rule #21).
  const int sw = (((l & 3) ^ ((l >> 3) & 3)) << 4);  // bytes
  const char* pA0[2];
  const char* pA1[2];
  const char* pA2[2];
  const char* pB[2];
#pragma unroll
  for (int r = 0; r < 2; ++r) {
    const int rl = w * 32 + r * 16 + (l >> 2);
    const int m = row0 + rl;
    if constexpr (IS_RELA) {
      const int b = m >> LOG_RPB;
      const int ri = m & ((1 << LOG_RPB) - 1);
      const int2 e =
          *reinterpret_cast<const int2*>(&edges[((size_t)b * kR + ri) * 2]);
      pA0[r] = (const char*)(objb + (size_t)(b * kN + e.x) * kD);
      pA1[r] = (const char*)(seg1b + (size_t)m * kD);
      pA2[r] = (const char*)(objb + (size_t)(b * kN + e.y) * kD);
    } else {
      pA0[r] = (const char*)(objb + (size_t)m * kD);
      pA1[r] = (const char*)(seg1b + (size_t)m * kD);
      pA2[r] = pA0[r];
    }
    pB[r] = (const char*)(Wb + (size_t)(col0 + rl) * K_TOT);
  }

  const int wr = w >> 2;
  const int wc = w & 3;
  const int lrow = l & 15;
  const int lgrp = l >> 4;
  const int pgr = ((lgrp ^ ((lrow >> 1) & 3)) << 3);  // shorts

  f32x4 acc[8][4] = {};
  bf16x8 AfX[4], AfY[4], Bf0[4], Bf1[4];

  // slot layout (shorts): S*32768 + { Ah0:0, Ah1:8192, Bh0:16384, Bh1:24576 }
  auto issueA = [&](int tn, int h, int slot) {
    unsigned short* ra = smem + slot * 32768 + h * 8192;
    const int kb = tn * 64 + h * 32;           // wave-uniform bf16 k-base
    const int seg = kb >> 10;
    const uint32_t ko = (uint32_t)(kb & 1023) * 2;
#pragma unroll
    for (int r = 0; r < 2; ++r) {
      const char* srcA;
      if constexpr (IS_RELA) {
        srcA = (seg == 1) ? pA1[r] : ((seg == 0) ? pA0[r] : pA2[r]);
      } else {
        srcA = (seg == 0) ? pA0[r] : pA1[r];
      }
      gload_lds16(srcA + ko + sw, ra + (w * 2 + r) * 512);
    }
  };
  auto issueB = [&](int tn, int h, int slot) {
    unsigned short* rb = smem + slot * 32768 + 16384 + h * 8192;
    const uint32_t kb2 = (uint32_t)(tn * 64 + h * 32) * 2;
#pragma unroll
    for (int r = 0; r < 2; ++r)
      gload_lds16(pB[r] + kb2 + sw, rb + (w * 2 + r) * 512);
  };

#define RD_A4(SET, SLOT, KK, MOFF)                                         \
  _Pragma("unroll")                                                        \
  for (int mi = 0; mi < 4; ++mi)                                           \
    SET[mi] = *reinterpret_cast<const bf16x8*>(                            \
        &smem[(SLOT) * 32768 + (KK) * 8192 +                               \
              (wr * 128 + ((MOFF) + mi) * 16 + lrow) * 32 + pgr]);

#define RD_B4(SET, SLOT, KK)                                               \
  _Pragma("unroll")                                                        \
  for (int ni = 0; ni < 4; ++ni)                                           \
    SET[ni] = *reinterpret_cast<const bf16x8*>(                            \
        &smem[(SLOT) * 32768 + 16384 + (KK) * 8192 +                       \
              (wc * 64 + ni * 16 + lrow) * 32 + pgr]);

#define MFMA16(MOFF, ASET, BSET)                                           \
  __builtin_amdgcn_s_setprio(1);                                           \
  _Pragma("unroll")                                                        \
  for (int mi = 0; mi < 4; ++mi)                                           \
    _Pragma("unroll")                                                      \
    for (int ni = 0; ni < 4; ++ni)                                         \
      acc[(MOFF) + mi][ni] = __builtin_amdgcn_mfma_f32_16x16x32_bf16(      \
          ASET[mi], BSET[ni], acc[(MOFF) + mi][ni], 0, 0, 0);              \
  __builtin_amdgcn_s_setprio(0);

// Super-tile t in slot S (compile-time 0/1); issues tile t+1 into S^1.
#define STILE(t, S)                                                        \
  {                                                                        \
    /* sp0 */                                                              \
    issueA((t) + 1, 0, (S) ^ 1);                                           \
    RD_A4(AfY, S, 0, 4);                                                   \
    MFMA16(0, AfX, Bf0);                                                   \
    /* sp1 */                                                              \
    issueB((t) + 1, 0, (S) ^ 1);                                           \
    WAITV(4);                                                              \
    __builtin_amdgcn_s_barrier();                                          \
    FENCE;                                                                 \
    RD_A4(AfX, S, 1, 0);                                                   \
    RD_B4(Bf1, S, 1);                                                      \
    MFMA16(4, AfY, Bf0);                                                   \
    /* sp2 */                                                              \
    issueA((t) + 1, 1, (S) ^ 1);                                           \
    RD_A4(AfY, S, 1, 4);                                                   \
    MFMA16(0, AfX, Bf1);                                                   \
    /* sp3 */                                                              \
    issueB((t) + 1, 1, (S) ^ 1);                                           \
    WAITV(4);                                                              \
    __builtin_amdgcn_s_barrier();                                          \
    FENCE;                                                                 \
    RD_A4(AfX, (S) ^ 1, 0, 0);                                             \
    RD_B4(Bf0, (S) ^ 1, 0);                                                \
    MFMA16(4, AfY, Bf1);                                                   \
  }

  // prologue: tile 0's four halves in steady-state order; half-0 resident.
  issueA(0, 0, 0); issueB(0, 0, 0);
  issueA(0, 1, 0); issueB(0, 1, 0);
  WAITV(4);  // Ah0,Bh0(0) landed; Ah1,Bh1(0) in flight
  __builtin_amdgcn_s_barrier();
  FENCE;
  RD_A4(AfX, 0, 0, 0);
  RD_B4(Bf0, 0, 0);

  // main loop: super-tiles 0 .. T-2 (T even: 48 rela / 32 attr)
#pragma unroll 1
  for (int it = 0; it < (T - 2) / 2; ++it) {
    STILE(2 * it, 0);
    STILE(2 * it + 1, 1);
  }
  STILE(T - 2, 0);  // issues tile T-1 into slot 1

  // tail: super-tile T-1 in slot 1, no issues.
  {
    RD_A4(AfY, 1, 0, 4);            // sp0
    MFMA16(0, AfX, Bf0);
    WAITV(0);                       // sp1: drain Ah1,Bh1(T-1)
    __builtin_amdgcn_s_barrier();
    FENCE;
    RD_A4(AfX, 1, 1, 0);
    RD_B4(Bf1, 1, 1);
    MFMA16(4, AfY, Bf0);
    RD_A4(AfY, 1, 1, 4);            // sp2
    MFMA16(0, AfX, Bf1);
    MFMA16(4, AfY, Bf1);            // sp3
  }

#undef STILE
#undef MFMA16
#undef RD_B4
#undef RD_A4

  // epilogue: bias + relu + residual (+mask)
  float biasv[4];
#pragma unroll
  for (int ni = 0; ni < 4; ++ni)
    biasv[ni] = bias[col0 + wc * 64 + ni * 16 + lrow];

#pragma unroll
  for (int mi = 0; mi < 8; ++mi) {
#pragma unroll
    for (int jj = 0; jj < 4; ++jj) {
      const int m = row0 + wr * 128 + mi * 16 + lgrp * 4 + jj;
      const size_t ro = (size_t)m * kD;
      float mk = 1.0f;
      if constexpr (IS_RELA) mk = masks[m];
#pragma unroll
      for (int ni = 0; ni < 4; ++ni) {
        const int col = col0 + wc * 64 + ni * 16 + lrow;
        float v = acc[mi][ni][jj] + biasv[ni];
        v = fmaxf(v, 0.0f) + resid[ro + col];
        if constexpr (IS_RELA) v *= mk;
        out[ro + col] = v;
      }
    }
  }
}

// ---------------------------------------------------------------------------
// Fused launch: blocks 0..1023 = rela GEMM, 1024..1151 = attr GEMM.
// ---------------------------------------------------------------------------
__global__ __launch_bounds__(512, 2) void gnn_fused(
    const unsigned short* __restrict__ objb,
    const unsigned short* __restrict__ attrb,
    const unsigned short* __restrict__ relab,
    const unsigned short* __restrict__ wab,
    const unsigned short* __restrict__ wrb,
    const int* __restrict__ edges, const float* __restrict__ masks,
    const float* __restrict__ attr, const float* __restrict__ rela,
    const float* __restrict__ b_attr, const float* __restrict__ b_rela,
    float* __restrict__ out1, float* __restrict__ out2) {
  extern __shared__ unsigned short smem[];
  const int bid = blockIdx.x;
  if (bid < 1024) {
    gemm_body<true, 3072, 11, 256>(bid, smem, objb, relab, wrb, edges, masks,
                                   rela, b_rela, out2);
  } else {
    gemm_body<false, 2048, 8, 32>(bid - 1024, smem, objb, attrb, wab, nullptr,
                                  nullptr, attr, b_attr, out1);
  }
}

extern "C" void kernel_launch(void* const* d_in, const int* in_sizes, int n_in,
                              void* d_out, int out_size, void* d_ws,
                              size_t ws_size, hipStream_t stream) {
  (void)in_sizes; (void)n_in; (void)out_size; (void)ws_size;
  const float* obj = (const float*)d_in[0];
  const float* attr = (const float*)d_in[1];
  const float* rela = (const float*)d_in[2];
  const int* edges = (const int*)d_in[3];
  const float* masks = (const float*)d_in[4];
  const float* W_attr = (const float*)d_in[5];
  const float* b_attr = (const float*)d_in[6];
  const float* W_rela = (const float*)d_in[7];
  const float* b_rela = (const float*)d_in[8];

  float* out0 = (float*)d_out;
  float* out1 = out0 + (size_t)kB * kN * kD;
  float* out2 = out1 + (size_t)kB * kN * kD;

  constexpr size_t nObj = (size_t)kB * kN * kD;
  constexpr size_t nRela = (size_t)kB * kR * kD;
  constexpr size_t nWa = (size_t)kD * 2 * kD;

  unsigned short* objb = (unsigned short*)d_ws;
  unsigned short* attrb = objb + nObj;
  unsigned short* relab = attrb + nObj;
  unsigned short* wab = relab + nRela;
  unsigned short* wrb = wab + nWa;

  cvt_all<<<2048, 256, 0, stream>>>(obj, attr, rela, W_attr, W_rela, objb,
                                    attrb, relab, wab, wrb, out0);

  constexpr int kSmem = 131072;
  hipFuncSetAttribute((const void*)gnn_fused,
                      hipFuncAttributeMaxDynamicSharedMemorySize, kSmem);
  gnn_fused<<<1152, 512, kSmem, stream>>>(objb, attrb, relab, wab, wrb, edges,
                                          masks, attr, rela, b_attr, b_rela,
                                          out1, out2);
}

// Round 16
// 453.852 us; speedup vs baseline: 3.3011x; 1.2498x over previous
//
#include <hip/hip_runtime.h>
#include <hip/hip_bf16.h>

constexpr int kB = 32;
constexpr int kN = 256;
constexpr int kR = 2048;
constexpr int kD = 1024;

typedef short bf16x8 __attribute__((ext_vector_type(8)));
typedef float f32x4 __attribute__((ext_vector_type(4)));
typedef unsigned short u16x8 __attribute__((ext_vector_type(8)));

__device__ __forceinline__ unsigned short f2bf(float f) {
  union { __hip_bfloat16 h; unsigned short u; } cv;
  cv.h = __float2bfloat16(f);
  return cv.u;
}
__device__ __forceinline__ float bf2f(unsigned short u) {
  union { unsigned int i; float f; } cv;
  cv.i = (unsigned int)u << 16;
  return cv.f;
}

__device__ __forceinline__ void gload_lds16(const void* g, void* l) {
  __builtin_amdgcn_global_load_lds(
      (const __attribute__((address_space(1))) unsigned int*)g,
      (__attribute__((address_space(3))) unsigned int*)l, 16, 0, 0);
}

#define FENCE asm volatile("" ::: "memory")
#define WAITV(n) asm volatile("s_waitcnt vmcnt(" #n ")" ::: "memory")

// ---------------------------------------------------------------------------
// Fused f32->bf16 pre-pass for all 5 GEMM operands + out0 passthrough copy.
// ---------------------------------------------------------------------------
__global__ void cvt_all(const float* __restrict__ obj,
                        const float* __restrict__ attr,
                        const float* __restrict__ rela,
                        const float* __restrict__ wa,
                        const float* __restrict__ wr,
                        unsigned short* __restrict__ objb,
                        unsigned short* __restrict__ attrb,
                        unsigned short* __restrict__ relab,
                        unsigned short* __restrict__ wab,
                        unsigned short* __restrict__ wrb,
                        float* __restrict__ out0) {
  constexpr long n0 = (long)kB * kN * kD / 8;          // obj
  constexpr long c0 = n0;
  constexpr long c1 = c0 + n0;                          // attr
  constexpr long c2 = c1 + (long)kB * kR * kD / 8;      // rela
  constexpr long c3 = c2 + (long)kD * 2 * kD / 8;       // W_attr
  constexpr long c4 = c3 + (long)kD * 3 * kD / 8;       // W_rela
  const long stride = (long)gridDim.x * blockDim.x;
  for (long i = (long)blockIdx.x * blockDim.x + threadIdx.x; i < c4;
       i += stride) {
    const float* s;
    unsigned short* d;
    long j;
    bool isobj = false;
    if (i < c0)      { s = obj;  d = objb;  j = i; isobj = true; }
    else if (i < c1) { s = attr; d = attrb; j = i - c0; }
    else if (i < c2) { s = rela; d = relab; j = i - c1; }
    else if (i < c3) { s = wa;   d = wab;   j = i - c2; }
    else             { s = wr;   d = wrb;   j = i - c3; }
    const float4 a = reinterpret_cast<const float4*>(s)[2 * j];
    const float4 b = reinterpret_cast<const float4*>(s)[2 * j + 1];
    if (isobj) {
      reinterpret_cast<float4*>(out0)[2 * j] = a;
      reinterpret_cast<float4*>(out0)[2 * j + 1] = b;
    }
    u16x8 v;
    v[0] = f2bf(a.x); v[1] = f2bf(a.y); v[2] = f2bf(a.z); v[3] = f2bf(a.w);
    v[4] = f2bf(b.x); v[5] = f2bf(b.y); v[6] = f2bf(b.z); v[7] = f2bf(b.w);
    reinterpret_cast<u16x8*>(d)[j] = v;
  }
}

// ---------------------------------------------------------------------------
// 256x256 bf16 GEMM body — R8-proven main loop (BK=64 super-tiles, 2-slot
// LDS double buffer, counted vmcnt(4), one-phase-ahead reads, setprio).
// MODE 0: attr    — A=[objb|attrb] by m, K=2048, full epilogue (no mask)
// MODE 1: relaOLD — A=[objb[subj]|relab|objb[obji]] gather, K=3072 (fallback)
// MODE 2: P-GEMM  — A=objb, K=1024, W stride 3072 + koffB; store raw bf16
// MODE 3: relaNEW — A=relab, K=1024, W stride 3072 + koffB(=W2); epilogue
//                   adds bias + P1b[subj] + P3b[obji], relu, +rela, *mask
// Algebraic split: gather commutes with matmul, so subj/obji contributions
// are precomputed at M=8192 (P1/P3) instead of K-concat at M=65536 —
// 446 -> 205 GFLOP total. P slabs are L2-hot in the epilogue (128 KB/block).
// ---------------------------------------------------------------------------
template <int MODE, int NPANEL>
__device__ __forceinline__ void gemm_body(
    int bid, unsigned short* smem,
    const unsigned short* __restrict__ srcA0,   // objb (0/1/2) or relab (3)
    const unsigned short* __restrict__ srcA1,   // attrb (0) / relab (1)
    const unsigned short* __restrict__ Wb, uint32_t koffB,
    const int* __restrict__ edges, const float* __restrict__ masks,
    const float* __restrict__ resid, const float* __restrict__ bias,
    const unsigned short* __restrict__ P1b,
    const unsigned short* __restrict__ P3b,
    float* __restrict__ outF, unsigned short* __restrict__ outP) {
  constexpr int K_TOT = (MODE == 0) ? 2048 : (MODE == 1) ? 3072 : 1024;
  constexpr int WST = (MODE == 0) ? 2048 : 3072;  // W row stride (elems)
  constexpr int T = K_TOT / 64;  // super-tiles

  // XCD mapping: XCD x owns col panel (x>>1); (x&1) splits row panels.
  const int x = bid & 7;
  const int col0 = (x >> 1) * 256;
  const int panel = (x & 1) * (NPANEL / 2) + (bid >> 3);
  const int row0 = panel * 256;

  const int tid = threadIdx.x;
  const int w = tid >> 6;   // wave 0..7
  const int l = tid & 63;

  // staging: round r of a half covers LDS rows (w*32 + r*16 + l>>2), granule
  // l&3 (16B); source pre-swizzle g=(l&3)^((l>>3)&3) (rule #21, verified).
  const int sw = (((l & 3) ^ ((l >> 3) & 3)) << 4);  // bytes
  const char* pA0[2];
  const char* pA1[2];
  const char* pA2[2];
  const char* pB[2];
#pragma unroll
  for (int r = 0; r < 2; ++r) {
    const int rl = w * 32 + r * 16 + (l >> 2);
    const int m = row0 + rl;
    if constexpr (MODE == 1) {
      const int b = m >> 11;
      const int ri = m & 2047;
      const int2 e =
          *reinterpret_cast<const int2*>(&edges[((size_t)b * kR + ri) * 2]);
      pA0[r] = (const char*)(srcA0 + (size_t)(b * kN + e.x) * kD);
      pA1[r] = (const char*)(srcA1 + (size_t)m * kD);
      pA2[r] = (const char*)(srcA0 + (size_t)(b * kN + e.y) * kD);
    } else {
      pA0[r] = (const char*)(srcA0 + (size_t)m * kD);
      pA1[r] = (MODE == 0) ? (const char*)(srcA1 + (size_t)m * kD) : pA0[r];
      pA2[r] = pA0[r];
    }
    pB[r] = (const char*)Wb + (size_t)(col0 + rl) * WST * 2 + koffB;
  }

  const int wr = w >> 2;
  const int wc = w & 3;
  const int lrow = l & 15;
  const int lgrp = l >> 4;
  const int pgr = ((lgrp ^ ((lrow >> 1) & 3)) << 3);  // shorts

  f32x4 acc[8][4] = {};
  bf16x8 AfX[4], AfY[4], Bf0[4], Bf1[4];

  // slot layout (shorts): S*32768 + { Ah0:0, Ah1:8192, Bh0:16384, Bh1:24576 }
  auto issueA = [&](int tn, int h, int slot) {
    unsigned short* ra = smem + slot * 32768 + h * 8192;
    const int kb = tn * 64 + h * 32;           // wave-uniform bf16 k-base
#pragma unroll
    for (int r = 0; r < 2; ++r) {
      const char* srcA;
      uint32_t ko;
      if constexpr (MODE == 1) {
        const int seg = kb >> 10;
        srcA = (seg == 1) ? pA1[r] : ((seg == 0) ? pA0[r] : pA2[r]);
        ko = (uint32_t)(kb & 1023) * 2;
      } else if constexpr (MODE == 0) {
        srcA = (kb < 1024) ? pA0[r] : pA1[r];
        ko = (uint32_t)(kb & 1023) * 2;
      } else {
        srcA = pA0[r];
        ko = (uint32_t)kb * 2;
      }
      gload_lds16(srcA + ko + sw, ra + (w * 2 + r) * 512);
    }
  };
  auto issueB = [&](int tn, int h, int slot) {
    unsigned short* rb = smem + slot * 32768 + 16384 + h * 8192;
    const uint32_t kb2 = (uint32_t)(tn * 64 + h * 32) * 2;
#pragma unroll
    for (int r = 0; r < 2; ++r)
      gload_lds16(pB[r] + kb2 + sw, rb + (w * 2 + r) * 512);
  };

#define RD_A4(SET, SLOT, KK, MOFF)                                         \
  _Pragma("unroll")                                                        \
  for (int mi = 0; mi < 4; ++mi)                                           \
    SET[mi] = *reinterpret_cast<const bf16x8*>(                            \
        &smem[(SLOT) * 32768 + (KK) * 8192 +                               \
              (wr * 128 + ((MOFF) + mi) * 16 + lrow) * 32 + pgr]);

#define RD_B4(SET, SLOT, KK)                                               \
  _Pragma("unroll")                                                        \
  for (int ni = 0; ni < 4; ++ni)                                           \
    SET[ni] = *reinterpret_cast<const bf16x8*>(                            \
        &smem[(SLOT) * 32768 + 16384 + (KK) * 8192 +                       \
              (wc * 64 + ni * 16 + lrow) * 32 + pgr]);

#define MFMA16(MOFF, ASET, BSET)                                           \
  __builtin_amdgcn_s_setprio(1);                                           \
  _Pragma("unroll")                                                        \
  for (int mi = 0; mi < 4; ++mi)                                           \
    _Pragma("unroll")                                                      \
    for (int ni = 0; ni < 4; ++ni)                                         \
      acc[(MOFF) + mi][ni] = __builtin_amdgcn_mfma_f32_16x16x32_bf16(      \
          ASET[mi], BSET[ni], acc[(MOFF) + mi][ni], 0, 0, 0);              \
  __builtin_amdgcn_s_setprio(0);

#define STILE(t, S)                                                        \
  {                                                                        \
    issueA((t) + 1, 0, (S) ^ 1);                                           \
    RD_A4(AfY, S, 0, 4);                                                   \
    MFMA16(0, AfX, Bf0);                                                   \
    issueB((t) + 1, 0, (S) ^ 1);                                           \
    WAITV(4);                                                              \
    __builtin_amdgcn_s_barrier();                                          \
    FENCE;                                                                 \
    RD_A4(AfX, S, 1, 0);                                                   \
    RD_B4(Bf1, S, 1);                                                      \
    MFMA16(4, AfY, Bf0);                                                   \
    issueA((t) + 1, 1, (S) ^ 1);                                           \
    RD_A4(AfY, S, 1, 4);                                                   \
    MFMA16(0, AfX, Bf1);                                                   \
    issueB((t) + 1, 1, (S) ^ 1);                                           \
    WAITV(4);                                                              \
    __builtin_amdgcn_s_barrier();                                          \
    FENCE;                                                                 \
    RD_A4(AfX, (S) ^ 1, 0, 0);                                             \
    RD_B4(Bf0, (S) ^ 1, 0);                                                \
    MFMA16(4, AfY, Bf1);                                                   \
  }

  // prologue
  issueA(0, 0, 0); issueB(0, 0, 0);
  issueA(0, 1, 0); issueB(0, 1, 0);
  WAITV(4);
  __builtin_amdgcn_s_barrier();
  FENCE;
  RD_A4(AfX, 0, 0, 0);
  RD_B4(Bf0, 0, 0);

  // main loop (T even)
#pragma unroll 1
  for (int it = 0; it < (T - 2) / 2; ++it) {
    STILE(2 * it, 0);
    STILE(2 * it + 1, 1);
  }
  STILE(T - 2, 0);

  // tail: super-tile T-1 in slot 1
  {
    RD_A4(AfY, 1, 0, 4);
    MFMA16(0, AfX, Bf0);
    WAITV(0);
    __builtin_amdgcn_s_barrier();
    FENCE;
    RD_A4(AfX, 1, 1, 0);
    RD_B4(Bf1, 1, 1);
    MFMA16(4, AfY, Bf0);
    RD_A4(AfY, 1, 1, 4);
    MFMA16(0, AfX, Bf1);
    MFMA16(4, AfY, Bf1);
  }

#undef STILE
#undef MFMA16
#undef RD_B4
#undef RD_A4

  // ---------------- epilogue ---------------------------------------------
  if constexpr (MODE == 2) {
    // raw bf16 store of acc into P buffer
#pragma unroll
    for (int mi = 0; mi < 8; ++mi) {
#pragma unroll
      for (int jj = 0; jj < 4; ++jj) {
        const int m = row0 + wr * 128 + mi * 16 + lgrp * 4 + jj;
        const size_t ro = (size_t)m * kD;
#pragma unroll
        for (int ni = 0; ni < 4; ++ni) {
          const int col = col0 + wc * 64 + ni * 16 + lrow;
          outP[ro + col] = f2bf(acc[mi][ni][jj]);
        }
      }
    }
    return;
  }

  float biasv[4];
#pragma unroll
  for (int ni = 0; ni < 4; ++ni)
    biasv[ni] = bias[col0 + wc * 64 + ni * 16 + lrow];

#pragma unroll
  for (int mi = 0; mi < 8; ++mi) {
#pragma unroll
    for (int jj = 0; jj < 4; ++jj) {
      const int m = row0 + wr * 128 + mi * 16 + lgrp * 4 + jj;
      const size_t ro = (size_t)m * kD;
      float mk = 1.0f;
      const unsigned short* p1row = nullptr;
      const unsigned short* p3row = nullptr;
      if constexpr (MODE == 1 || MODE == 3) mk = masks[m];
      if constexpr (MODE == 3) {
        const int b = m >> 11;
        const int2 e = reinterpret_cast<const int2*>(edges)[m];
        p1row = P1b + (size_t)(b * kN + e.x) * kD;
        p3row = P3b + (size_t)(b * kN + e.y) * kD;
      }
#pragma unroll
      for (int ni = 0; ni < 4; ++ni) {
        const int col = col0 + wc * 64 + ni * 16 + lrow;
        float v = acc[mi][ni][jj] + biasv[ni];
        if constexpr (MODE == 3) v += bf2f(p1row[col]) + bf2f(p3row[col]);
        v = fmaxf(v, 0.0f) + resid[ro + col];
        if constexpr (MODE == 1 || MODE == 3) v *= mk;
        outF[ro + col] = v;
      }
    }
  }
}

// ---------------------------------------------------------------------------
// Launch A (split path): bid 0..127 attr, 128..255 P1, 256..383 P3 (M=8192).
// ---------------------------------------------------------------------------
__global__ __launch_bounds__(512, 2) void gnn_small(
    const unsigned short* __restrict__ objb,
    const unsigned short* __restrict__ attrb,
    const unsigned short* __restrict__ wab,
    const unsigned short* __restrict__ wrb,
    const float* __restrict__ attr, const float* __restrict__ b_attr,
    float* __restrict__ out1, unsigned short* __restrict__ p1b,
    unsigned short* __restrict__ p3b) {
  extern __shared__ unsigned short smem[];
  const int bid = blockIdx.x;
  if (bid < 128) {
    gemm_body<0, 32>(bid, smem, objb, attrb, wab, 0, nullptr, nullptr, attr,
                     b_attr, nullptr, nullptr, out1, nullptr);
  } else if (bid < 256) {
    gemm_body<2, 32>(bid - 128, smem, objb, nullptr, wrb, 0, nullptr, nullptr,
                     nullptr, nullptr, nullptr, nullptr, nullptr, p1b);
  } else {
    gemm_body<2, 32>(bid - 256, smem, objb, nullptr, wrb, 4096, nullptr,
                     nullptr, nullptr, nullptr, nullptr, nullptr, nullptr,
                     p3b);
  }
}

// ---------------------------------------------------------------------------
// Launch B (split path): rela main GEMM, K=1024, 1024 blocks.
// ---------------------------------------------------------------------------
__global__ __launch_bounds__(512, 2) void gnn_rela(
    const unsigned short* __restrict__ relab,
    const unsigned short* __restrict__ wrb,
    const int* __restrict__ edges, const float* __restrict__ masks,
    const float* __restrict__ rela, const float* __restrict__ b_rela,
    const unsigned short* __restrict__ p1b,
    const unsigned short* __restrict__ p3b, float* __restrict__ out2) {
  extern __shared__ unsigned short smem[];
  gemm_body<3, 256>(blockIdx.x, smem, relab, nullptr, wrb, 2048, edges, masks,
                    rela, b_rela, p1b, p3b, out2, nullptr);
}

// ---------------------------------------------------------------------------
// Fallback (R8 proven path): blocks 0..1023 rela full-K, 1024..1151 attr.
// ---------------------------------------------------------------------------
__global__ __launch_bounds__(512, 2) void gnn_fused(
    const unsigned short* __restrict__ objb,
    const unsigned short* __restrict__ attrb,
    const unsigned short* __restrict__ relab,
    const unsigned short* __restrict__ wab,
    const unsigned short* __restrict__ wrb,
    const int* __restrict__ edges, const float* __restrict__ masks,
    const float* __restrict__ attr, const float* __restrict__ rela,
    const float* __restrict__ b_attr, const float* __restrict__ b_rela,
    float* __restrict__ out1, float* __restrict__ out2) {
  extern __shared__ unsigned short smem[];
  const int bid = blockIdx.x;
  if (bid < 1024) {
    gemm_body<1, 256>(bid, smem, objb, relab, wrb, 0, edges, masks, rela,
                      b_rela, nullptr, nullptr, out2, nullptr);
  } else {
    gemm_body<0, 32>(bid - 1024, smem, objb, attrb, wab, 0, nullptr, nullptr,
                     attr, b_attr, nullptr, nullptr, out1, nullptr);
  }
}

extern "C" void kernel_launch(void* const* d_in, const int* in_sizes, int n_in,
                              void* d_out, int out_size, void* d_ws,
                              size_t ws_size, hipStream_t stream) {
  (void)in_sizes; (void)n_in; (void)out_size;
  const float* obj = (const float*)d_in[0];
  const float* attr = (const float*)d_in[1];
  const float* rela = (const float*)d_in[2];
  const int* edges = (const int*)d_in[3];
  const float* masks = (const float*)d_in[4];
  const float* W_attr = (const float*)d_in[5];
  const float* b_attr = (const float*)d_in[6];
  const float* W_rela = (const float*)d_in[7];
  const float* b_rela = (const float*)d_in[8];

  float* out0 = (float*)d_out;
  float* out1 = out0 + (size_t)kB * kN * kD;
  float* out2 = out1 + (size_t)kB * kN * kD;

  constexpr size_t nObj = (size_t)kB * kN * kD;
  constexpr size_t nRela = (size_t)kB * kR * kD;
  constexpr size_t nWa = (size_t)kD * 2 * kD;
  constexpr size_t nWr = (size_t)kD * 3 * kD;

  unsigned short* objb = (unsigned short*)d_ws;
  unsigned short* attrb = objb + nObj;
  unsigned short* relab = attrb + nObj;
  unsigned short* wab = relab + nRela;
  unsigned short* wrb = wab + nWa;
  unsigned short* p1b = wrb + nWr;
  unsigned short* p3b = p1b + nObj;

  constexpr size_t WS_SPLIT = (nObj * 4 + nRela + nWa + nWr) * 2;

  cvt_all<<<2048, 256, 0, stream>>>(obj, attr, rela, W_attr, W_rela, objb,
                                    attrb, relab, wab, wrb, out0);

  constexpr int kSmem = 131072;
  if (ws_size >= WS_SPLIT) {
    hipFuncSetAttribute((const void*)gnn_small,
                        hipFuncAttributeMaxDynamicSharedMemorySize, kSmem);
    hipFuncSetAttribute((const void*)gnn_rela,
                        hipFuncAttributeMaxDynamicSharedMemorySize, kSmem);
    gnn_small<<<384, 512, kSmem, stream>>>(objb, attrb, wab, wrb, attr,
                                           b_attr, out1, p1b, p3b);
    gnn_rela<<<1024, 512, kSmem, stream>>>(relab, wrb, edges, masks, rela,
                                           b_rela, p1b, p3b, out2);
  } else {
    hipFuncSetAttribute((const void*)gnn_fused,
                        hipFuncAttributeMaxDynamicSharedMemorySize, kSmem);
    gnn_fused<<<1152, 512, kSmem, stream>>>(objb, attrb, relab, wab, wrb,
                                            edges, masks, attr, rela, b_attr,
                                            b_rela, out1, out2);
  }
}

// Round 17
// 422.265 us; speedup vs baseline: 3.5480x; 1.0748x over previous
//
#include <hip/hip_runtime.h>
#include <hip/hip_bf16.h>

constexpr int kB = 32;
constexpr int kN = 256;
constexpr int kR = 2048;
constexpr int kD = 1024;

typedef short bf16x8 __attribute__((ext_vector_type(8)));
typedef float f32x4 __attribute__((ext_vector_type(4)));
typedef unsigned short u16x8 __attribute__((ext_vector_type(8)));

__device__ __forceinline__ unsigned short f2bf(float f) {
  union { __hip_bfloat16 h; unsigned short u; } cv;
  cv.h = __float2bfloat16(f);
  return cv.u;
}
__device__ __forceinline__ float bf2f(unsigned short u) {
  union { unsigned int i; float f; } cv;
  cv.i = (unsigned int)u << 16;
  return cv.f;
}

__device__ __forceinline__ void gload_lds16(const void* g, void* l) {
  __builtin_amdgcn_global_load_lds(
      (const __attribute__((address_space(1))) unsigned int*)g,
      (__attribute__((address_space(3))) unsigned int*)l, 16, 0, 0);
}

#define FENCE asm volatile("" ::: "memory")
#define WAITV(n) asm volatile("s_waitcnt vmcnt(" #n ")" ::: "memory")

// ---------------------------------------------------------------------------
// Fused f32->bf16 pre-pass for all 5 GEMM operands + out0 passthrough copy.
// ---------------------------------------------------------------------------
__global__ void cvt_all(const float* __restrict__ obj,
                        const float* __restrict__ attr,
                        const float* __restrict__ rela,
                        const float* __restrict__ wa,
                        const float* __restrict__ wr,
                        unsigned short* __restrict__ objb,
                        unsigned short* __restrict__ attrb,
                        unsigned short* __restrict__ relab,
                        unsigned short* __restrict__ wab,
                        unsigned short* __restrict__ wrb,
                        float* __restrict__ out0) {
  constexpr long n0 = (long)kB * kN * kD / 8;          // obj
  constexpr long c0 = n0;
  constexpr long c1 = c0 + n0;                          // attr
  constexpr long c2 = c1 + (long)kB * kR * kD / 8;      // rela
  constexpr long c3 = c2 + (long)kD * 2 * kD / 8;       // W_attr
  constexpr long c4 = c3 + (long)kD * 3 * kD / 8;       // W_rela
  const long stride = (long)gridDim.x * blockDim.x;
  for (long i = (long)blockIdx.x * blockDim.x + threadIdx.x; i < c4;
       i += stride) {
    const float* s;
    unsigned short* d;
    long j;
    bool isobj = false;
    if (i < c0)      { s = obj;  d = objb;  j = i; isobj = true; }
    else if (i < c1) { s = attr; d = attrb; j = i - c0; }
    else if (i < c2) { s = rela; d = relab; j = i - c1; }
    else if (i < c3) { s = wa;   d = wab;   j = i - c2; }
    else             { s = wr;   d = wrb;   j = i - c3; }
    const float4 a = reinterpret_cast<const float4*>(s)[2 * j];
    const float4 b = reinterpret_cast<const float4*>(s)[2 * j + 1];
    if (isobj) {
      reinterpret_cast<float4*>(out0)[2 * j] = a;
      reinterpret_cast<float4*>(out0)[2 * j + 1] = b;
    }
    u16x8 v;
    v[0] = f2bf(a.x); v[1] = f2bf(a.y); v[2] = f2bf(a.z); v[3] = f2bf(a.w);
    v[4] = f2bf(b.x); v[5] = f2bf(b.y); v[6] = f2bf(b.z); v[7] = f2bf(b.w);
    reinterpret_cast<u16x8*>(d)[j] = v;
  }
}

// ---------------------------------------------------------------------------
// 256x256 bf16 GEMM body — R8-proven main loop (BK=64 super-tiles, 2-slot
// LDS double buffer, counted vmcnt(4), one-phase-ahead reads, setprio).
// MODE 0: attr    — A=[objb|attrb] by m, K=2048; resid = attrb (bf16)
// MODE 1: relaOLD — A=gathered concat, K=3072 (fallback); resid = relab
// MODE 2: P-GEMM  — A=objb, K=1024, W stride 3072 + koffB; store raw bf16
// MODE 3: relaNEW — A=relab, K=1024, W stride 3072 + koffB(=W2); epilogue
//                   adds bias + P1b[subj] + P3b[obji], relu, +relab, *mask
// R17: epilogue residual reads the bf16 copy (residB) — saves 134 MB HBM on
// rela, 17 MB on attr; out stores are nontemporal (never re-read) to keep
// the P slabs L2-resident during the gather epilogue.
// ---------------------------------------------------------------------------
template <int MODE, int NPANEL>
__device__ __forceinline__ void gemm_body(
    int bid, unsigned short* smem,
    const unsigned short* __restrict__ srcA0,   // objb (0/1/2) or relab (3)
    const unsigned short* __restrict__ srcA1,   // attrb (0) / relab (1)
    const unsigned short* __restrict__ Wb, uint32_t koffB,
    const int* __restrict__ edges, const float* __restrict__ masks,
    const unsigned short* __restrict__ residB, const float* __restrict__ bias,
    const unsigned short* __restrict__ P1b,
    const unsigned short* __restrict__ P3b,
    float* __restrict__ outF, unsigned short* __restrict__ outP) {
  constexpr int K_TOT = (MODE == 0) ? 2048 : (MODE == 1) ? 3072 : 1024;
  constexpr int WST = (MODE == 0) ? 2048 : 3072;  // W row stride (elems)
  constexpr int T = K_TOT / 64;  // super-tiles

  // XCD mapping: XCD x owns col panel (x>>1); (x&1) splits row panels.
  const int x = bid & 7;
  const int col0 = (x >> 1) * 256;
  const int panel = (x & 1) * (NPANEL / 2) + (bid >> 3);
  const int row0 = panel * 256;

  const int tid = threadIdx.x;
  const int w = tid >> 6;   // wave 0..7
  const int l = tid & 63;

  // staging: round r of a half covers LDS rows (w*32 + r*16 + l>>2), granule
  // l&3 (16B); source pre-swizzle g=(l&3)^((l>>3)&3) (rule #21, verified).
  const int sw = (((l & 3) ^ ((l >> 3) & 3)) << 4);  // bytes
  const char* pA0[2];
  const char* pA1[2];
  const char* pA2[2];
  const char* pB[2];
#pragma unroll
  for (int r = 0; r < 2; ++r) {
    const int rl = w * 32 + r * 16 + (l >> 2);
    const int m = row0 + rl;
    if constexpr (MODE == 1) {
      const int b = m >> 11;
      const int ri = m & 2047;
      const int2 e =
          *reinterpret_cast<const int2*>(&edges[((size_t)b * kR + ri) * 2]);
      pA0[r] = (const char*)(srcA0 + (size_t)(b * kN + e.x) * kD);
      pA1[r] = (const char*)(srcA1 + (size_t)m * kD);
      pA2[r] = (const char*)(srcA0 + (size_t)(b * kN + e.y) * kD);
    } else {
      pA0[r] = (const char*)(srcA0 + (size_t)m * kD);
      pA1[r] = (MODE == 0) ? (const char*)(srcA1 + (size_t)m * kD) : pA0[r];
      pA2[r] = pA0[r];
    }
    pB[r] = (const char*)Wb + (size_t)(col0 + rl) * WST * 2 + koffB;
  }

  const int wr = w >> 2;
  const int wc = w & 3;
  const int lrow = l & 15;
  const int lgrp = l >> 4;
  const int pgr = ((lgrp ^ ((lrow >> 1) & 3)) << 3);  // shorts

  f32x4 acc[8][4] = {};
  bf16x8 AfX[4], AfY[4], Bf0[4], Bf1[4];

  // slot layout (shorts): S*32768 + { Ah0:0, Ah1:8192, Bh0:16384, Bh1:24576 }
  auto issueA = [&](int tn, int h, int slot) {
    unsigned short* ra = smem + slot * 32768 + h * 8192;
    const int kb = tn * 64 + h * 32;           // wave-uniform bf16 k-base
#pragma unroll
    for (int r = 0; r < 2; ++r) {
      const char* srcA;
      uint32_t ko;
      if constexpr (MODE == 1) {
        const int seg = kb >> 10;
        srcA = (seg == 1) ? pA1[r] : ((seg == 0) ? pA0[r] : pA2[r]);
        ko = (uint32_t)(kb & 1023) * 2;
      } else if constexpr (MODE == 0) {
        srcA = (kb < 1024) ? pA0[r] : pA1[r];
        ko = (uint32_t)(kb & 1023) * 2;
      } else {
        srcA = pA0[r];
        ko = (uint32_t)kb * 2;
      }
      gload_lds16(srcA + ko + sw, ra + (w * 2 + r) * 512);
    }
  };
  auto issueB = [&](int tn, int h, int slot) {
    unsigned short* rb = smem + slot * 32768 + 16384 + h * 8192;
    const uint32_t kb2 = (uint32_t)(tn * 64 + h * 32) * 2;
#pragma unroll
    for (int r = 0; r < 2; ++r)
      gload_lds16(pB[r] + kb2 + sw, rb + (w * 2 + r) * 512);
  };

#define RD_A4(SET, SLOT, KK, MOFF)                                         \
  _Pragma("unroll")                                                        \
  for (int mi = 0; mi < 4; ++mi)                                           \
    SET[mi] = *reinterpret_cast<const bf16x8*>(                            \
        &smem[(SLOT) * 32768 + (KK) * 8192 +                               \
              (wr * 128 + ((MOFF) + mi) * 16 + lrow) * 32 + pgr]);

#define RD_B4(SET, SLOT, KK)                                               \
  _Pragma("unroll")                                                        \
  for (int ni = 0; ni < 4; ++ni)                                           \
    SET[ni] = *reinterpret_cast<const bf16x8*>(                            \
        &smem[(SLOT) * 32768 + 16384 + (KK) * 8192 +                       \
              (wc * 64 + ni * 16 + lrow) * 32 + pgr]);

#define MFMA16(MOFF, ASET, BSET)                                           \
  __builtin_amdgcn_s_setprio(1);                                           \
  _Pragma("unroll")                                                        \
  for (int mi = 0; mi < 4; ++mi)                                           \
    _Pragma("unroll")                                                      \
    for (int ni = 0; ni < 4; ++ni)                                         \
      acc[(MOFF) + mi][ni] = __builtin_amdgcn_mfma_f32_16x16x32_bf16(      \
          ASET[mi], BSET[ni], acc[(MOFF) + mi][ni], 0, 0, 0);              \
  __builtin_amdgcn_s_setprio(0);

#define STILE(t, S)                                                        \
  {                                                                        \
    issueA((t) + 1, 0, (S) ^ 1);                                           \
    RD_A4(AfY, S, 0, 4);                                                   \
    MFMA16(0, AfX, Bf0);                                                   \
    issueB((t) + 1, 0, (S) ^ 1);                                           \
    WAITV(4);                                                              \
    __builtin_amdgcn_s_barrier();                                          \
    FENCE;                                                                 \
    RD_A4(AfX, S, 1, 0);                                                   \
    RD_B4(Bf1, S, 1);                                                      \
    MFMA16(4, AfY, Bf0);                                                   \
    issueA((t) + 1, 1, (S) ^ 1);                                           \
    RD_A4(AfY, S, 1, 4);                                                   \
    MFMA16(0, AfX, Bf1);                                                   \
    issueB((t) + 1, 1, (S) ^ 1);                                           \
    WAITV(4);                                                              \
    __builtin_amdgcn_s_barrier();                                          \
    FENCE;                                                                 \
    RD_A4(AfX, (S) ^ 1, 0, 0);                                             \
    RD_B4(Bf0, (S) ^ 1, 0);                                                \
    MFMA16(4, AfY, Bf1);                                                   \
  }

  // prologue
  issueA(0, 0, 0); issueB(0, 0, 0);
  issueA(0, 1, 0); issueB(0, 1, 0);
  WAITV(4);
  __builtin_amdgcn_s_barrier();
  FENCE;
  RD_A4(AfX, 0, 0, 0);
  RD_B4(Bf0, 0, 0);

  // main loop (T even)
#pragma unroll 1
  for (int it = 0; it < (T - 2) / 2; ++it) {
    STILE(2 * it, 0);
    STILE(2 * it + 1, 1);
  }
  STILE(T - 2, 0);

  // tail: super-tile T-1 in slot 1
  {
    RD_A4(AfY, 1, 0, 4);
    MFMA16(0, AfX, Bf0);
    WAITV(0);
    __builtin_amdgcn_s_barrier();
    FENCE;
    RD_A4(AfX, 1, 1, 0);
    RD_B4(Bf1, 1, 1);
    MFMA16(4, AfY, Bf0);
    RD_A4(AfY, 1, 1, 4);
    MFMA16(0, AfX, Bf1);
    MFMA16(4, AfY, Bf1);
  }

#undef STILE
#undef MFMA16
#undef RD_B4
#undef RD_A4

  // ---------------- epilogue ---------------------------------------------
  if constexpr (MODE == 2) {
#pragma unroll
    for (int mi = 0; mi < 8; ++mi) {
#pragma unroll
      for (int jj = 0; jj < 4; ++jj) {
        const int m = row0 + wr * 128 + mi * 16 + lgrp * 4 + jj;
        const size_t ro = (size_t)m * kD;
#pragma unroll
        for (int ni = 0; ni < 4; ++ni) {
          const int col = col0 + wc * 64 + ni * 16 + lrow;
          outP[ro + col] = f2bf(acc[mi][ni][jj]);
        }
      }
    }
    return;
  }

  float biasv[4];
#pragma unroll
  for (int ni = 0; ni < 4; ++ni)
    biasv[ni] = bias[col0 + wc * 64 + ni * 16 + lrow];

#pragma unroll
  for (int mi = 0; mi < 8; ++mi) {
#pragma unroll
    for (int jj = 0; jj < 4; ++jj) {
      const int m = row0 + wr * 128 + mi * 16 + lgrp * 4 + jj;
      const size_t ro = (size_t)m * kD;
      float mk = 1.0f;
      const unsigned short* p1row = nullptr;
      const unsigned short* p3row = nullptr;
      if constexpr (MODE == 1 || MODE == 3) mk = masks[m];
      if constexpr (MODE == 3) {
        const int b = m >> 11;
        const int2 e = reinterpret_cast<const int2*>(edges)[m];
        p1row = P1b + (size_t)(b * kN + e.x) * kD;
        p3row = P3b + (size_t)(b * kN + e.y) * kD;
      }
#pragma unroll
      for (int ni = 0; ni < 4; ++ni) {
        const int col = col0 + wc * 64 + ni * 16 + lrow;
        float v = acc[mi][ni][jj] + biasv[ni];
        if constexpr (MODE == 3) v += bf2f(p1row[col]) + bf2f(p3row[col]);
        v = fmaxf(v, 0.0f) + bf2f(residB[ro + col]);
        if constexpr (MODE == 1 || MODE == 3) v *= mk;
        __builtin_nontemporal_store(v, &outF[ro + col]);
      }
    }
  }
}

// ---------------------------------------------------------------------------
// Launch A (split path): bid 0..127 attr, 128..255 P1, 256..383 P3 (M=8192).
// ---------------------------------------------------------------------------
__global__ __launch_bounds__(512, 2) void gnn_small(
    const unsigned short* __restrict__ objb,
    const unsigned short* __restrict__ attrb,
    const unsigned short* __restrict__ wab,
    const unsigned short* __restrict__ wrb,
    const float* __restrict__ b_attr,
    float* __restrict__ out1, unsigned short* __restrict__ p1b,
    unsigned short* __restrict__ p3b) {
  extern __shared__ unsigned short smem[];
  const int bid = blockIdx.x;
  if (bid < 128) {
    gemm_body<0, 32>(bid, smem, objb, attrb, wab, 0, nullptr, nullptr, attrb,
                     b_attr, nullptr, nullptr, out1, nullptr);
  } else if (bid < 256) {
    gemm_body<2, 32>(bid - 128, smem, objb, nullptr, wrb, 0, nullptr, nullptr,
                     nullptr, nullptr, nullptr, nullptr, nullptr, p1b);
  } else {
    gemm_body<2, 32>(bid - 256, smem, objb, nullptr, wrb, 4096, nullptr,
                     nullptr, nullptr, nullptr, nullptr, nullptr, nullptr,
                     p3b);
  }
}

// ---------------------------------------------------------------------------
// Launch B (split path): rela main GEMM, K=1024, 1024 blocks.
// ---------------------------------------------------------------------------
__global__ __launch_bounds__(512, 2) void gnn_rela(
    const unsigned short* __restrict__ relab,
    const unsigned short* __restrict__ wrb,
    const int* __restrict__ edges, const float* __restrict__ masks,
    const float* __restrict__ b_rela,
    const unsigned short* __restrict__ p1b,
    const unsigned short* __restrict__ p3b, float* __restrict__ out2) {
  extern __shared__ unsigned short smem[];
  gemm_body<3, 256>(blockIdx.x, smem, relab, nullptr, wrb, 2048, edges, masks,
                    relab, b_rela, p1b, p3b, out2, nullptr);
}

// ---------------------------------------------------------------------------
// Fallback (R8 proven path): blocks 0..1023 rela full-K, 1024..1151 attr.
// ---------------------------------------------------------------------------
__global__ __launch_bounds__(512, 2) void gnn_fused(
    const unsigned short* __restrict__ objb,
    const unsigned short* __restrict__ attrb,
    const unsigned short* __restrict__ relab,
    const unsigned short* __restrict__ wab,
    const unsigned short* __restrict__ wrb,
    const int* __restrict__ edges, const float* __restrict__ masks,
    const float* __restrict__ b_attr, const float* __restrict__ b_rela,
    float* __restrict__ out1, float* __restrict__ out2) {
  extern __shared__ unsigned short smem[];
  const int bid = blockIdx.x;
  if (bid < 1024) {
    gemm_body<1, 256>(bid, smem, objb, relab, wrb, 0, edges, masks, relab,
                      b_rela, nullptr, nullptr, out2, nullptr);
  } else {
    gemm_body<0, 32>(bid - 1024, smem, objb, attrb, wab, 0, nullptr, nullptr,
                     attrb, b_attr, nullptr, nullptr, out1, nullptr);
  }
}

extern "C" void kernel_launch(void* const* d_in, const int* in_sizes, int n_in,
                              void* d_out, int out_size, void* d_ws,
                              size_t ws_size, hipStream_t stream) {
  (void)in_sizes; (void)n_in; (void)out_size;
  const float* obj = (const float*)d_in[0];
  const float* attr = (const float*)d_in[1];
  const float* rela = (const float*)d_in[2];
  const int* edges = (const int*)d_in[3];
  const float* masks = (const float*)d_in[4];
  const float* W_attr = (const float*)d_in[5];
  const float* b_attr = (const float*)d_in[6];
  const float* W_rela = (const float*)d_in[7];
  const float* b_rela = (const float*)d_in[8];

  float* out0 = (float*)d_out;
  float* out1 = out0 + (size_t)kB * kN * kD;
  float* out2 = out1 + (size_t)kB * kN * kD;

  constexpr size_t nObj = (size_t)kB * kN * kD;
  constexpr size_t nRela = (size_t)kB * kR * kD;
  constexpr size_t nWa = (size_t)kD * 2 * kD;
  constexpr size_t nWr = (size_t)kD * 3 * kD;

  unsigned short* objb = (unsigned short*)d_ws;
  unsigned short* attrb = objb + nObj;
  unsigned short* relab = attrb + nObj;
  unsigned short* wab = relab + nRela;
  unsigned short* wrb = wab + nWa;
  unsigned short* p1b = wrb + nWr;
  unsigned short* p3b = p1b + nObj;

  constexpr size_t WS_SPLIT = (nObj * 4 + nRela + nWa + nWr) * 2;

  cvt_all<<<2048, 256, 0, stream>>>(obj, attr, rela, W_attr, W_rela, objb,
                                    attrb, relab, wab, wrb, out0);

  constexpr int kSmem = 131072;
  if (ws_size >= WS_SPLIT) {
    hipFuncSetAttribute((const void*)gnn_small,
                        hipFuncAttributeMaxDynamicSharedMemorySize, kSmem);
    hipFuncSetAttribute((const void*)gnn_rela,
                        hipFuncAttributeMaxDynamicSharedMemorySize, kSmem);
    gnn_small<<<384, 512, kSmem, stream>>>(objb, attrb, wab, wrb, b_attr,
                                           out1, p1b, p3b);
    gnn_rela<<<1024, 512, kSmem, stream>>>(relab, wrb, edges, masks, b_rela,
                                           p1b, p3b, out2);
  } else {
    hipFuncSetAttribute((const void*)gnn_fused,
                        hipFuncAttributeMaxDynamicSharedMemorySize, kSmem);
    gnn_fused<<<1152, 512, kSmem, stream>>>(objb, attrb, relab, wab, wrb,
                                            edges, masks, b_attr, b_rela,
                                            out1, out2);
  }
}

// Round 18
// 419.257 us; speedup vs baseline: 3.5735x; 1.0072x over previous
//
#include <hip/hip_runtime.h>
#include <hip/hip_bf16.h>

constexpr int kB = 32;
constexpr int kN = 256;
constexpr int kR = 2048;
constexpr int kD = 1024;

typedef short bf16x8 __attribute__((ext_vector_type(8)));
typedef float f32x4 __attribute__((ext_vector_type(4)));
typedef unsigned short u16x8 __attribute__((ext_vector_type(8)));

__device__ __forceinline__ unsigned short f2bf(float f) {
  union { __hip_bfloat16 h; unsigned short u; } cv;
  cv.h = __float2bfloat16(f);
  return cv.u;
}
__device__ __forceinline__ float bf2f(unsigned short u) {
  union { unsigned int i; float f; } cv;
  cv.i = (unsigned int)u << 16;
  return cv.f;
}

__device__ __forceinline__ void gload_lds16(const void* g, void* l) {
  __builtin_amdgcn_global_load_lds(
      (const __attribute__((address_space(1))) unsigned int*)g,
      (__attribute__((address_space(3))) unsigned int*)l, 16, 0, 0);
}

#define FENCE asm volatile("" ::: "memory")
#define WAITV(n) asm volatile("s_waitcnt vmcnt(" #n ")" ::: "memory")

__device__ __forceinline__ void cvt8(const float* __restrict__ s,
                                     unsigned short* __restrict__ d, long j) {
  const float4 a = reinterpret_cast<const float4*>(s)[2 * j];
  const float4 b = reinterpret_cast<const float4*>(s)[2 * j + 1];
  u16x8 v;
  v[0] = f2bf(a.x); v[1] = f2bf(a.y); v[2] = f2bf(a.z); v[3] = f2bf(a.w);
  v[4] = f2bf(b.x); v[5] = f2bf(b.y); v[6] = f2bf(b.z); v[7] = f2bf(b.w);
  reinterpret_cast<u16x8*>(d)[j] = v;
}

// ---------------------------------------------------------------------------
// cvt_front: obj/attr/W_attr/W_rela -> bf16, + out0 passthrough (no rela).
// ---------------------------------------------------------------------------
__global__ void cvt_front(const float* __restrict__ obj,
                          const float* __restrict__ attr,
                          const float* __restrict__ wa,
                          const float* __restrict__ wr,
                          unsigned short* __restrict__ objb,
                          unsigned short* __restrict__ attrb,
                          unsigned short* __restrict__ wab,
                          unsigned short* __restrict__ wrb,
                          float* __restrict__ out0) {
  constexpr long n0 = (long)kB * kN * kD / 8;
  constexpr long c0 = n0;
  constexpr long c1 = c0 + n0;
  constexpr long c2 = c1 + (long)kD * 2 * kD / 8;
  constexpr long c3 = c2 + (long)kD * 3 * kD / 8;
  const long stride = (long)gridDim.x * blockDim.x;
  for (long i = (long)blockIdx.x * blockDim.x + threadIdx.x; i < c3;
       i += stride) {
    if (i < c0) {
      const float4 a = reinterpret_cast<const float4*>(obj)[2 * i];
      const float4 b = reinterpret_cast<const float4*>(obj)[2 * i + 1];
      reinterpret_cast<float4*>(out0)[2 * i] = a;
      reinterpret_cast<float4*>(out0)[2 * i + 1] = b;
      u16x8 v;
      v[0] = f2bf(a.x); v[1] = f2bf(a.y); v[2] = f2bf(a.z); v[3] = f2bf(a.w);
      v[4] = f2bf(b.x); v[5] = f2bf(b.y); v[6] = f2bf(b.z); v[7] = f2bf(b.w);
      reinterpret_cast<u16x8*>(objb)[i] = v;
    } else if (i < c1) {
      cvt8(attr, attrb, i - c0);
    } else if (i < c2) {
      cvt8(wa, wab, i - c1);
    } else {
      cvt8(wr, wrb, i - c2);
    }
  }
}

// ---------------------------------------------------------------------------
// cvt_all (fallback path only): all 5 operands + out0.
// ---------------------------------------------------------------------------
__global__ void cvt_all(const float* __restrict__ obj,
                        const float* __restrict__ attr,
                        const float* __restrict__ rela,
                        const float* __restrict__ wa,
                        const float* __restrict__ wr,
                        unsigned short* __restrict__ objb,
                        unsigned short* __restrict__ attrb,
                        unsigned short* __restrict__ relab,
                        unsigned short* __restrict__ wab,
                        unsigned short* __restrict__ wrb,
                        float* __restrict__ out0) {
  constexpr long n0 = (long)kB * kN * kD / 8;
  constexpr long c0 = n0;
  constexpr long c1 = c0 + n0;
  constexpr long c2 = c1 + (long)kB * kR * kD / 8;
  constexpr long c3 = c2 + (long)kD * 2 * kD / 8;
  constexpr long c4 = c3 + (long)kD * 3 * kD / 8;
  const long stride = (long)gridDim.x * blockDim.x;
  for (long i = (long)blockIdx.x * blockDim.x + threadIdx.x; i < c4;
       i += stride) {
    if (i < c0) {
      const float4 a = reinterpret_cast<const float4*>(obj)[2 * i];
      const float4 b = reinterpret_cast<const float4*>(obj)[2 * i + 1];
      reinterpret_cast<float4*>(out0)[2 * i] = a;
      reinterpret_cast<float4*>(out0)[2 * i + 1] = b;
      u16x8 v;
      v[0] = f2bf(a.x); v[1] = f2bf(a.y); v[2] = f2bf(a.z); v[3] = f2bf(a.w);
      v[4] = f2bf(b.x); v[5] = f2bf(b.y); v[6] = f2bf(b.z); v[7] = f2bf(b.w);
      reinterpret_cast<u16x8*>(objb)[i] = v;
    } else if (i < c1) cvt8(attr, attrb, i - c0);
    else if (i < c2) cvt8(rela, relab, i - c1);
    else if (i < c3) cvt8(wa, wab, i - c2);
    else cvt8(wr, wrb, i - c3);
  }
}

// ---------------------------------------------------------------------------
// 256x256 bf16 GEMM body — R8-proven main loop (BK=64 super-tiles, 2-slot
// LDS double buffer, counted vmcnt(4), one-phase-ahead reads, setprio).
// MODE 0: attr    — A=[objb|attrb] by m, K=2048; resid = attrb (bf16)
// MODE 1: relaOLD — A=gathered concat, K=3072 (fallback); resid = relab
// MODE 2: P-GEMM  — A=objb, K=1024, W stride 3072 + koffB; store raw bf16
// MODE 3: relaNEW — A=relab, K=1024, W stride 3072 + koffB(=W2); epilogue
//                   adds bias + P1b[subj] + P3b[obji], relu, +relab, *mask
// Epilogue residual reads the bf16 copy; out stores nontemporal.
// ---------------------------------------------------------------------------
template <int MODE, int NPANEL>
__device__ __forceinline__ void gemm_body(
    int bid, unsigned short* smem,
    const unsigned short* __restrict__ srcA0,
    const unsigned short* __restrict__ srcA1,
    const unsigned short* __restrict__ Wb, uint32_t koffB,
    const int* __restrict__ edges, const float* __restrict__ masks,
    const unsigned short* __restrict__ residB, const float* __restrict__ bias,
    const unsigned short* __restrict__ P1b,
    const unsigned short* __restrict__ P3b,
    float* __restrict__ outF, unsigned short* __restrict__ outP) {
  constexpr int K_TOT = (MODE == 0) ? 2048 : (MODE == 1) ? 3072 : 1024;
  constexpr int WST = (MODE == 0) ? 2048 : 3072;  // W row stride (elems)
  constexpr int T = K_TOT / 64;  // super-tiles

  const int x = bid & 7;
  const int col0 = (x >> 1) * 256;
  const int panel = (x & 1) * (NPANEL / 2) + (bid >> 3);
  const int row0 = panel * 256;

  const int tid = threadIdx.x;
  const int w = tid >> 6;
  const int l = tid & 63;

  const int sw = (((l & 3) ^ ((l >> 3) & 3)) << 4);  // bytes
  const char* pA0[2];
  const char* pA1[2];
  const char* pA2[2];
  const char* pB[2];
#pragma unroll
  for (int r = 0; r < 2; ++r) {
    const int rl = w * 32 + r * 16 + (l >> 2);
    const int m = row0 + rl;
    if constexpr (MODE == 1) {
      const int b = m >> 11;
      const int ri = m & 2047;
      const int2 e =
          *reinterpret_cast<const int2*>(&edges[((size_t)b * kR + ri) * 2]);
      pA0[r] = (const char*)(srcA0 + (size_t)(b * kN + e.x) * kD);
      pA1[r] = (const char*)(srcA1 + (size_t)m * kD);
      pA2[r] = (const char*)(srcA0 + (size_t)(b * kN + e.y) * kD);
    } else {
      pA0[r] = (const char*)(srcA0 + (size_t)m * kD);
      pA1[r] = (MODE == 0) ? (const char*)(srcA1 + (size_t)m * kD) : pA0[r];
      pA2[r] = pA0[r];
    }
    pB[r] = (const char*)Wb + (size_t)(col0 + rl) * WST * 2 + koffB;
  }

  const int wr = w >> 2;
  const int wc = w & 3;
  const int lrow = l & 15;
  const int lgrp = l >> 4;
  const int pgr = ((lgrp ^ ((lrow >> 1) & 3)) << 3);  // shorts

  f32x4 acc[8][4] = {};
  bf16x8 AfX[4], AfY[4], Bf0[4], Bf1[4];

  auto issueA = [&](int tn, int h, int slot) {
    unsigned short* ra = smem + slot * 32768 + h * 8192;
    const int kb = tn * 64 + h * 32;
#pragma unroll
    for (int r = 0; r < 2; ++r) {
      const char* srcA;
      uint32_t ko;
      if constexpr (MODE == 1) {
        const int seg = kb >> 10;
        srcA = (seg == 1) ? pA1[r] : ((seg == 0) ? pA0[r] : pA2[r]);
        ko = (uint32_t)(kb & 1023) * 2;
      } else if constexpr (MODE == 0) {
        srcA = (kb < 1024) ? pA0[r] : pA1[r];
        ko = (uint32_t)(kb & 1023) * 2;
      } else {
        srcA = pA0[r];
        ko = (uint32_t)kb * 2;
      }
      gload_lds16(srcA + ko + sw, ra + (w * 2 + r) * 512);
    }
  };
  auto issueB = [&](int tn, int h, int slot) {
    unsigned short* rb = smem + slot * 32768 + 16384 + h * 8192;
    const uint32_t kb2 = (uint32_t)(tn * 64 + h * 32) * 2;
#pragma unroll
    for (int r = 0; r < 2; ++r)
      gload_lds16(pB[r] + kb2 + sw, rb + (w * 2 + r) * 512);
  };

#define RD_A4(SET, SLOT, KK, MOFF)                                         \
  _Pragma("unroll")                                                        \
  for (int mi = 0; mi < 4; ++mi)                                           \
    SET[mi] = *reinterpret_cast<const bf16x8*>(                            \
        &smem[(SLOT) * 32768 + (KK) * 8192 +                               \
              (wr * 128 + ((MOFF) + mi) * 16 + lrow) * 32 + pgr]);

#define RD_B4(SET, SLOT, KK)                                               \
  _Pragma("unroll")                                                        \
  for (int ni = 0; ni < 4; ++ni)                                           \
    SET[ni] = *reinterpret_cast<const bf16x8*>(                            \
        &smem[(SLOT) * 32768 + 16384 + (KK) * 8192 +                       \
              (wc * 64 + ni * 16 + lrow) * 32 + pgr]);

#define MFMA16(MOFF, ASET, BSET)                                           \
  __builtin_amdgcn_s_setprio(1);                                           \
  _Pragma("unroll")                                                        \
  for (int mi = 0; mi < 4; ++mi)                                           \
    _Pragma("unroll")                                                      \
    for (int ni = 0; ni < 4; ++ni)                                         \
      acc[(MOFF) + mi][ni] = __builtin_amdgcn_mfma_f32_16x16x32_bf16(      \
          ASET[mi], BSET[ni], acc[(MOFF) + mi][ni], 0, 0, 0);              \
  __builtin_amdgcn_s_setprio(0);

#define STILE(t, S)                                                        \
  {                                                                        \
    issueA((t) + 1, 0, (S) ^ 1);                                           \
    RD_A4(AfY, S, 0, 4);                                                   \
    MFMA16(0, AfX, Bf0);                                                   \
    issueB((t) + 1, 0, (S) ^ 1);                                           \
    WAITV(4);                                                              \
    __builtin_amdgcn_s_barrier();                                          \
    FENCE;                                                                 \
    RD_A4(AfX, S, 1, 0);                                                   \
    RD_B4(Bf1, S, 1);                                                      \
    MFMA16(4, AfY, Bf0);                                                   \
    issueA((t) + 1, 1, (S) ^ 1);                                           \
    RD_A4(AfY, S, 1, 4);                                                   \
    MFMA16(0, AfX, Bf1);                                                   \
    issueB((t) + 1, 1, (S) ^ 1);                                           \
    WAITV(4);                                                              \
    __builtin_amdgcn_s_barrier();                                          \
    FENCE;                                                                 \
    RD_A4(AfX, (S) ^ 1, 0, 0);                                             \
    RD_B4(Bf0, (S) ^ 1, 0);                                                \
    MFMA16(4, AfY, Bf1);                                                   \
  }

  // prologue
  issueA(0, 0, 0); issueB(0, 0, 0);
  issueA(0, 1, 0); issueB(0, 1, 0);
  WAITV(4);
  __builtin_amdgcn_s_barrier();
  FENCE;
  RD_A4(AfX, 0, 0, 0);
  RD_B4(Bf0, 0, 0);

  // main loop (T even)
#pragma unroll 1
  for (int it = 0; it < (T - 2) / 2; ++it) {
    STILE(2 * it, 0);
    STILE(2 * it + 1, 1);
  }
  STILE(T - 2, 0);

  // tail
  {
    RD_A4(AfY, 1, 0, 4);
    MFMA16(0, AfX, Bf0);
    WAITV(0);
    __builtin_amdgcn_s_barrier();
    FENCE;
    RD_A4(AfX, 1, 1, 0);
    RD_B4(Bf1, 1, 1);
    MFMA16(4, AfY, Bf0);
    RD_A4(AfY, 1, 1, 4);
    MFMA16(0, AfX, Bf1);
    MFMA16(4, AfY, Bf1);
  }

#undef STILE
#undef MFMA16
#undef RD_B4
#undef RD_A4

  // ---------------- epilogue ---------------------------------------------
  if constexpr (MODE == 2) {
#pragma unroll
    for (int mi = 0; mi < 8; ++mi) {
#pragma unroll
      for (int jj = 0; jj < 4; ++jj) {
        const int m = row0 + wr * 128 + mi * 16 + lgrp * 4 + jj;
        const size_t ro = (size_t)m * kD;
#pragma unroll
        for (int ni = 0; ni < 4; ++ni) {
          const int col = col0 + wc * 64 + ni * 16 + lrow;
          outP[ro + col] = f2bf(acc[mi][ni][jj]);
        }
      }
    }
    return;
  }

  float biasv[4];
#pragma unroll
  for (int ni = 0; ni < 4; ++ni)
    biasv[ni] = bias[col0 + wc * 64 + ni * 16 + lrow];

#pragma unroll
  for (int mi = 0; mi < 8; ++mi) {
#pragma unroll
    for (int jj = 0; jj < 4; ++jj) {
      const int m = row0 + wr * 128 + mi * 16 + lgrp * 4 + jj;
      const size_t ro = (size_t)m * kD;
      float mk = 1.0f;
      const unsigned short* p1row = nullptr;
      const unsigned short* p3row = nullptr;
      if constexpr (MODE == 1 || MODE == 3) mk = masks[m];
      if constexpr (MODE == 3) {
        const int b = m >> 11;
        const int2 e = reinterpret_cast<const int2*>(edges)[m];
        p1row = P1b + (size_t)(b * kN + e.x) * kD;
        p3row = P3b + (size_t)(b * kN + e.y) * kD;
      }
#pragma unroll
      for (int ni = 0; ni < 4; ++ni) {
        const int col = col0 + wc * 64 + ni * 16 + lrow;
        float v = acc[mi][ni][jj] + biasv[ni];
        if constexpr (MODE == 3) v += bf2f(p1row[col]) + bf2f(p3row[col]);
        v = fmaxf(v, 0.0f) + bf2f(residB[ro + col]);
        if constexpr (MODE == 1 || MODE == 3) v *= mk;
        __builtin_nontemporal_store(v, &outF[ro + col]);
      }
    }
  }
}

// ---------------------------------------------------------------------------
// Combined launch: blocks 0..127 attr GEMM, 128..255 P1, 256..383 P3;
// blocks 384..2047 stream-convert rela -> relab (overlaps GEMM compute).
// relab is consumed only by the NEXT dispatch (gnn_rela) — no intra-kernel
// dependency.
// ---------------------------------------------------------------------------
__global__ __launch_bounds__(512, 2) void gnn_small_cvt(
    const unsigned short* __restrict__ objb,
    const unsigned short* __restrict__ attrb,
    const unsigned short* __restrict__ wab,
    const unsigned short* __restrict__ wrb,
    const float* __restrict__ b_attr, float* __restrict__ out1,
    unsigned short* __restrict__ p1b, unsigned short* __restrict__ p3b,
    const float* __restrict__ rela, unsigned short* __restrict__ relab) {
  extern __shared__ unsigned short smem[];
  const int bid = blockIdx.x;
  if (bid < 128) {
    gemm_body<0, 32>(bid, smem, objb, attrb, wab, 0, nullptr, nullptr, attrb,
                     b_attr, nullptr, nullptr, out1, nullptr);
  } else if (bid < 256) {
    gemm_body<2, 32>(bid - 128, smem, objb, nullptr, wrb, 0, nullptr, nullptr,
                     nullptr, nullptr, nullptr, nullptr, nullptr, p1b);
  } else if (bid < 384) {
    gemm_body<2, 32>(bid - 256, smem, objb, nullptr, wrb, 4096, nullptr,
                     nullptr, nullptr, nullptr, nullptr, nullptr, nullptr,
                     p3b);
  } else {
    constexpr long n8 = (long)kB * kR * kD / 8;
    const long nth = (long)(2048 - 384) * 512;
    for (long i = (long)(bid - 384) * 512 + threadIdx.x; i < n8; i += nth)
      cvt8(rela, relab, i);
  }
}

// ---------------------------------------------------------------------------
// rela main GEMM, K=1024, 1024 blocks.
// ---------------------------------------------------------------------------
__global__ __launch_bounds__(512, 2) void gnn_rela(
    const unsigned short* __restrict__ relab,
    const unsigned short* __restrict__ wrb,
    const int* __restrict__ edges, const float* __restrict__ masks,
    const float* __restrict__ b_rela,
    const unsigned short* __restrict__ p1b,
    const unsigned short* __restrict__ p3b, float* __restrict__ out2) {
  extern __shared__ unsigned short smem[];
  gemm_body<3, 256>(blockIdx.x, smem, relab, nullptr, wrb, 2048, edges, masks,
                    relab, b_rela, p1b, p3b, out2, nullptr);
}

// ---------------------------------------------------------------------------
// Fallback (R8 proven path): blocks 0..1023 rela full-K, 1024..1151 attr.
// ---------------------------------------------------------------------------
__global__ __launch_bounds__(512, 2) void gnn_fused(
    const unsigned short* __restrict__ objb,
    const unsigned short* __restrict__ attrb,
    const unsigned short* __restrict__ relab,
    const unsigned short* __restrict__ wab,
    const unsigned short* __restrict__ wrb,
    const int* __restrict__ edges, const float* __restrict__ masks,
    const float* __restrict__ b_attr, const float* __restrict__ b_rela,
    float* __restrict__ out1, float* __restrict__ out2) {
  extern __shared__ unsigned short smem[];
  const int bid = blockIdx.x;
  if (bid < 1024) {
    gemm_body<1, 256>(bid, smem, objb, relab, wrb, 0, edges, masks, relab,
                      b_rela, nullptr, nullptr, out2, nullptr);
  } else {
    gemm_body<0, 32>(bid - 1024, smem, objb, attrb, wab, 0, nullptr, nullptr,
                     attrb, b_attr, nullptr, nullptr, out1, nullptr);
  }
}

extern "C" void kernel_launch(void* const* d_in, const int* in_sizes, int n_in,
                              void* d_out, int out_size, void* d_ws,
                              size_t ws_size, hipStream_t stream) {
  (void)in_sizes; (void)n_in; (void)out_size;
  const float* obj = (const float*)d_in[0];
  const float* attr = (const float*)d_in[1];
  const float* rela = (const float*)d_in[2];
  const int* edges = (const int*)d_in[3];
  const float* masks = (const float*)d_in[4];
  const float* W_attr = (const float*)d_in[5];
  const float* b_attr = (const float*)d_in[6];
  const float* W_rela = (const float*)d_in[7];
  const float* b_rela = (const float*)d_in[8];

  float* out0 = (float*)d_out;
  float* out1 = out0 + (size_t)kB * kN * kD;
  float* out2 = out1 + (size_t)kB * kN * kD;

  constexpr size_t nObj = (size_t)kB * kN * kD;
  constexpr size_t nRela = (size_t)kB * kR * kD;
  constexpr size_t nWa = (size_t)kD * 2 * kD;
  constexpr size_t nWr = (size_t)kD * 3 * kD;

  unsigned short* objb = (unsigned short*)d_ws;
  unsigned short* attrb = objb + nObj;
  unsigned short* relab = attrb + nObj;
  unsigned short* wab = relab + nRela;
  unsigned short* wrb = wab + nWa;
  unsigned short* p1b = wrb + nWr;
  unsigned short* p3b = p1b + nObj;

  constexpr size_t WS_SPLIT = (nObj * 4 + nRela + nWa + nWr) * 2;
  constexpr int kSmem = 131072;

  if (ws_size >= WS_SPLIT) {
    cvt_front<<<2048, 256, 0, stream>>>(obj, attr, W_attr, W_rela, objb,
                                        attrb, wab, wrb, out0);
    hipFuncSetAttribute((const void*)gnn_small_cvt,
                        hipFuncAttributeMaxDynamicSharedMemorySize, kSmem);
    hipFuncSetAttribute((const void*)gnn_rela,
                        hipFuncAttributeMaxDynamicSharedMemorySize, kSmem);
    gnn_small_cvt<<<2048, 512, kSmem, stream>>>(objb, attrb, wab, wrb, b_attr,
                                                out1, p1b, p3b, rela, relab);
    gnn_rela<<<1024, 512, kSmem, stream>>>(relab, wrb, edges, masks, b_rela,
                                           p1b, p3b, out2);
  } else {
    cvt_all<<<2048, 256, 0, stream>>>(obj, attr, rela, W_attr, W_rela, objb,
                                      attrb, relab, wab, wrb, out0);
    hipFuncSetAttribute((const void*)gnn_fused,
                        hipFuncAttributeMaxDynamicSharedMemorySize, kSmem);
    gnn_fused<<<1152, 512, kSmem, stream>>>(objb, attrb, relab, wab, wrb,
                                            edges, masks, b_attr, b_rela,
                                            out1, out2);
  }
}